// Round 2
// baseline (1770.015 us; speedup 1.0000x reference)
//
#include <hip/hip_runtime.h>

// CHIVE clockwork RNN, fp32.
// Block = 256 threads = 8 batch chains x 32 hidden lanes; grid = 256 -> B=2048.
// v2 (resubmit after infra failure): recurrent state lives in REGISTERS
// (1 element/lane). The all-to-all "broadcast" for h @ Wh is done with DPP
// row_ror:1 register rotation (+ one ds_swizzle xor16 to cross 16-lane row
// halves) against per-lane PRE-PERMUTED weight columns. This removes the
// ds_read_b128 broadcast storm that made v1 LDS-issue-bound (~32 DS
// instr/wave/step x 4 waves/CU ~ 1280 cyc/CU/step). Only x-input staging
// stays in LDS.

constexpr int TS  = 2048;  // timesteps
constexpr int B   = 2048;  // batch
constexpr int HH  = 32;    // hidden
constexpr int CH  = 16;    // timesteps per staged chunk
constexpr int NCH = TS / CH;
constexpr int BPB = 8;     // batch per block

__device__ __forceinline__ float fast_tanh(float x) {
    x = fminf(fmaxf(x, -9.0f), 9.0f);
    float e = __expf(2.0f * x);
    return (e - 1.0f) * __builtin_amdgcn_rcpf(e + 1.0f);
}

// rotate-by-1 within each 16-lane row (DPP row_ror:1), pure VALU
__device__ __forceinline__ float rotr1(float x) {
    int i = __float_as_int(x);
    i = __builtin_amdgcn_update_dpp(i, i, 0x121, 0xF, 0xF, false);
    return __int_as_float(i);
}

// swap 16-lane row halves within each 32-lane group (lane ^= 16)
__device__ __forceinline__ float swap16(float x) {
    return __int_as_float(__builtin_amdgcn_ds_swizzle(__float_as_int(x), 0x401F));
}

// 32-term dot product: hval is register-distributed (lane k of the 32-lane
// group holds element k), W is a 32-entry per-lane register array holding the
// weight column pre-permuted to match the rotation schedule.
#define GDOT32(res, hval, W) do {                                   \
    float _ra = (hval);                                             \
    float _rb = swap16(_ra);                                        \
    float _aA = 0.f, _aB = 0.f;                                     \
    _Pragma("unroll")                                               \
    for (int _s = 0; _s < 16; _s++) {                               \
        _aA = fmaf(_ra, W[_s], _aA);                                \
        _aB = fmaf(_rb, W[16 + _s], _aB);                           \
        if (_s < 15) { _ra = rotr1(_ra); _rb = rotr1(_rb); }        \
    }                                                               \
    (res) = _aA + _aB;                                              \
} while (0)

__global__ __launch_bounds__(256, 1)
void chive_rnn(const float* __restrict__ frnn, const float* __restrict__ phrnn,
               const float* __restrict__ syl,
               const float* __restrict__ Wxf, const float* __restrict__ Whf,
               const float* __restrict__ bf,
               const float* __restrict__ Wxp, const float* __restrict__ Whp,
               const float* __restrict__ bp,
               const float* __restrict__ Wxs, const float* __restrict__ Whs,
               const float* __restrict__ bs,
               const int* __restrict__ fclock, const int* __restrict__ pclock,
               const int* __restrict__ sfreq, float* __restrict__ out)
{
    __shared__ __align__(16) float xfb[2][CH][BPB * 8];
    __shared__ __align__(16) float xpb[2][CH][BPB * 8];
    __shared__ __align__(16) float xsb[2][CH][BPB * 32];  // 24 data + 8 zero pad per chain
    __shared__ int gates[TS];

    const int tid = threadIdx.x;
    const int j   = tid & 31;   // hidden index (element this lane owns)
    const int g   = tid >> 5;   // batch-in-block
    const int b0  = blockIdx.x * BPB;
    const int p   = j & 15;     // position within 16-lane row
    const int R   = j >> 4;     // row half within the 32-lane group

    // ---- DPP direction probe: is row_ror:1 "lane p <- lane p-1" or "<- p+1"?
    int pr = __builtin_amdgcn_update_dpp(p, p, 0x121, 0xF, 0xF, false);
    const int dir = (pr == ((p - 1) & 15)) ? 1 : -1;

    // ---- per-lane weight columns, pre-permuted for the rotation schedule ----
    // After s rotations, this lane holds element k = Re*16 + ((p - dir*s)&15),
    // where Re = R for s<16 (own half) and 1-R for s>=16 (after swap16).
    float whf_r[32], whp_r[32], wxs_r[32], whs_r[32];
#pragma unroll
    for (int s = 0; s < 32; s++) {
        int Re = (s < 16) ? R : 1 - R;
        int k  = Re * 16 + ((p - dir * s) & 15);
        whf_r[s] = Whf[k * HH + j];
        whp_r[s] = Whp[k * HH + j];
        wxs_r[s] = Wxs[k * HH + j];
        whs_r[s] = Whs[k * HH + j];
    }
    float wxf[8], wxp[8];
#pragma unroll
    for (int i = 0; i < 8; i++) { wxf[i] = Wxf[i * HH + j]; wxp[i] = Wxp[i * HH + j]; }
    const float bfj = bf[j], bpj = bp[j], bsj = bs[j];

    // ---- chunk staging (register prefetch -> LDS double buffer) ----
    float4 rf, rp, rs0, rs1, rs2;
    const int tl = tid >> 4;   // 0..15: timestep within chunk this thread loads
    const int q  = tid & 15;   // 0..15: float4 slot within the row
    // syl source row is 8 chains x 24 floats; dest row is 8 chains x 32 floats.
    // 24 % 4 == 0 so no float4 straddles a chain boundary.
    const int ss0 = q * 4, ss1 = 64 + q * 4, ss2 = 128 + q * 4;
    const int d0 = (ss0 / 24) * 32 + (ss0 % 24);
    const int d1 = (ss1 / 24) * 32 + (ss1 % 24);
    const int d2 = (ss2 / 24) * 32 + (ss2 % 24);

    auto load_chunk = [&](int ch) {
        const size_t t  = (size_t)ch * CH + tl;
        const float* fb = frnn  + (t * B + b0) * 8;
        const float* pb = phrnn + (t * B + b0) * 8;
        const float* sb = syl   + (t * B + b0) * 24;
        rf  = *(const float4*)(fb + q * 4);
        rp  = *(const float4*)(pb + q * 4);
        rs0 = *(const float4*)(sb + ss0);
        rs1 = *(const float4*)(sb + ss1);
        rs2 = *(const float4*)(sb + ss2);
    };
    auto store_chunk = [&](int buf) {
        *(float4*)&xfb[buf][tl][q * 4] = rf;
        *(float4*)&xpb[buf][tl][q * 4] = rp;
        *(float4*)&xsb[buf][tl][d0]    = rs0;
        *(float4*)&xsb[buf][tl][d1]    = rs1;
        *(float4*)&xsb[buf][tl][d2]    = rs2;
    };

    load_chunk(0);

    // ---- zero the syl pad columns once (stores never touch them again) ----
    {
        const int bb = tid >> 7, rr = (tid >> 3) & 15, cc = tid & 7;
        float4 z = {0.f, 0.f, 0.f, 0.f};
        *(float4*)&xsb[bb][rr][cc * 32 + 24] = z;
        *(float4*)&xsb[bb][rr][cc * 32 + 28] = z;
    }

    // ---- gate precompute ----
    for (int i = tid; i < TS; i += 256) {
        int mf = fclock[i] + 1;
        int mp = pclock[i] + 1;
        int v = 0;
        if ((i % mf) == 0)  v |= 1;
        if ((i % mp) == 0)  v |= 2;
        if (sfreq[i] == 1)  v |= 4;
        gates[i] = v;
    }

    // ---- state in registers: lane j owns element j of each vector ----
    float hfv = 0.f, hpv = 0.f, hs0 = 0.f, hs1 = 0.f, hs2 = 0.f;
    float s0x = 0.f, s1x = 0.f;          // cached hf@Wxs / hp@Wxs (per-lane j)
    bool fdirty = false, pdirty = false; // wave-uniform

    store_chunk(0);
    __syncthreads();

    int cur = 0;
#pragma unroll 1
    for (int ch = 0; ch < NCH; ch++) {
        if (ch + 1 < NCH) load_chunk(ch + 1);   // prefetch next chunk into regs

#pragma unroll 1
        for (int c = 0; c < CH; c++) {
            const int t  = ch * CH + c;
            const int gt = __builtin_amdgcn_readfirstlane(gates[t]);

            // ---------- f cell ----------
            if (gt & 1) {
                const float4* xv = (const float4*)&xfb[cur][c][g * 8];
                float4 x0 = xv[0], x1 = xv[1];
                float a = bfj;
                a = fmaf(x0.x, wxf[0], a); a = fmaf(x0.y, wxf[1], a);
                a = fmaf(x0.z, wxf[2], a); a = fmaf(x0.w, wxf[3], a);
                a = fmaf(x1.x, wxf[4], a); a = fmaf(x1.y, wxf[5], a);
                a = fmaf(x1.z, wxf[6], a); a = fmaf(x1.w, wxf[7], a);
                float hh; GDOT32(hh, hfv, whf_r);
                hfv = fast_tanh(a + hh);
                fdirty = true;
            }

            // ---------- p cell ----------
            if (gt & 2) {
                const float4* xv = (const float4*)&xpb[cur][c][g * 8];
                float4 x0 = xv[0], x1 = xv[1];
                float a = bpj;
                a = fmaf(x0.x, wxp[0], a); a = fmaf(x0.y, wxp[1], a);
                a = fmaf(x0.z, wxp[2], a); a = fmaf(x0.w, wxp[3], a);
                a = fmaf(x1.x, wxp[4], a); a = fmaf(x1.y, wxp[5], a);
                a = fmaf(x1.z, wxp[6], a); a = fmaf(x1.w, wxp[7], a);
                float hh; GDOT32(hh, hpv, whp_r);
                hpv = fast_tanh(a + hh);
                pdirty = true;
            }

            // ---------- syl cell: x = {hf_new, hp_new, x_syl(padded)} ----------
            if (gt & 4) {
                if (fdirty) { GDOT32(s0x, hfv, wxs_r); fdirty = false; }
                if (pdirty) { GDOT32(s1x, hpv, wxs_r); pdirty = false; }
                float xs = xsb[cur][c][g * 32 + j];   // per-lane, pad j>=24 is 0
                float s2x; GDOT32(s2x, xs,  wxs_r);
                float m0;  GDOT32(m0,  hs0, whs_r);
                float m1;  GDOT32(m1,  hs1, whs_r);
                float m2;  GDOT32(m2,  hs2, whs_r);
                hs0 = fast_tanh(bsj + s0x + m0);
                hs1 = fast_tanh(bsj + s1x + m1);
                hs2 = fast_tanh(bsj + s2x + m2);
            }
        }

        if (ch + 1 < NCH) store_chunk(cur ^ 1);
        __syncthreads();
        cur ^= 1;
    }

    // ---- output: h_s final, [3, B, H] ----
    const int b = b0 + g;
    out[((size_t)0 * B + b) * HH + j] = hs0;
    out[((size_t)1 * B + b) * HH + j] = hs1;
    out[((size_t)2 * B + b) * HH + j] = hs2;
}

extern "C" void kernel_launch(void* const* d_in, const int* in_sizes, int n_in,
                              void* d_out, int out_size, void* d_ws, size_t ws_size,
                              hipStream_t stream) {
    const float* frnn  = (const float*)d_in[0];
    const float* phrnn = (const float*)d_in[1];
    const float* syl   = (const float*)d_in[2];
    const float* Wxf   = (const float*)d_in[3];
    const float* Whf   = (const float*)d_in[4];
    const float* bf    = (const float*)d_in[5];
    const float* Wxp   = (const float*)d_in[6];
    const float* Whp   = (const float*)d_in[7];
    const float* bp    = (const float*)d_in[8];
    const float* Wxs   = (const float*)d_in[9];
    const float* Whs   = (const float*)d_in[10];
    const float* bs    = (const float*)d_in[11];
    const int* fclock  = (const int*)d_in[12];
    const int* pclock  = (const int*)d_in[13];
    const int* sfreq   = (const int*)d_in[14];
    float* out = (float*)d_out;

    dim3 grid(B / BPB);   // 256 blocks
    dim3 block(256);
    chive_rnn<<<grid, block, 0, stream>>>(frnn, phrnn, syl,
                                          Wxf, Whf, bf, Wxp, Whp, bp,
                                          Wxs, Whs, bs,
                                          fclock, pclock, sfreq, out);
}